// Round 7
// baseline (501.780 us; speedup 1.0000x reference)
//
#include <hip/hip_runtime.h>
#include <hip/hip_bf16.h>

#define Bn 32
#define Sn 2048
#define Hn 2048
#define Qn 1024
#define Mn (Bn * Sn)

typedef __attribute__((ext_vector_type(8))) short bf16x8;
typedef __attribute__((ext_vector_type(4))) float f32x4;

__device__ __forceinline__ unsigned short f2bf(float x) {
  unsigned int u = __float_as_uint(x);
  unsigned int r = (u + 0x7FFFu + ((u >> 16) & 1u)) >> 16;  // RNE
  return (unsigned short)r;
}

__device__ __forceinline__ float bf2f(short s) {
  return __uint_as_float(((unsigned int)(unsigned short)s) << 16);
}

__device__ __forceinline__ unsigned int cvtpk(float lo, float hi) {
  unsigned int r;
  asm("v_cvt_pk_bf16_f32 %0, %1, %2" : "=v"(r) : "v"(lo), "v"(hi));
  return r;
}

__device__ __forceinline__ void gload16(const void* g, void* l) {
  __builtin_amdgcn_global_load_lds(
      (const __attribute__((address_space(1))) unsigned int*)g,
      (__attribute__((address_space(3))) unsigned int*)l, 16, 0, 0);
}

// ---------------- rnn f32 -> bf16 (grid-stride, 8 elems/thread/iter) --------
__global__ void cvt_rnn_kernel(const float* __restrict__ in,
                               unsigned short* __restrict__ out) {
  const size_t total8 = (size_t)Mn * Hn / 8;
  size_t i = (size_t)blockIdx.x * 256 + threadIdx.x;
  const size_t stride = (size_t)gridDim.x * 256;
  for (; i < total8; i += stride) {
    float4 v0 = ((const float4*)in)[i * 2];
    float4 v1 = ((const float4*)in)[i * 2 + 1];
    union { unsigned int u[4]; bf16x8 v; } pk;
    pk.u[0] = cvtpk(v0.x, v0.y);
    pk.u[1] = cvtpk(v0.z, v0.w);
    pk.u[2] = cvtpk(v1.x, v1.y);
    pk.u[3] = cvtpk(v1.z, v1.w);
    *(bf16x8*)(out + i * 8) = pk.v;
  }
}

// ---------------- c1[b,q] = sum_k rev[b,k] * Wa[q,k] ------------------------
__global__ void c1_kernel(const float* __restrict__ rev,
                          const float* __restrict__ Wa,
                          float* __restrict__ c1) {
  int wid = (blockIdx.x * 256 + threadIdx.x) >> 6;
  int lane = threadIdx.x & 63;
  int b = wid >> 10;
  int q = wid & (Qn - 1);
  const float* rv = rev + (size_t)b * Qn;
  const float* wr = Wa + (size_t)q * Qn;
  float acc = 0.f;
#pragma unroll
  for (int k = 0; k < Qn; k += 64) acc += rv[k + lane] * wr[k + lane];
#pragma unroll
  for (int m = 32; m > 0; m >>= 1) acc += __shfl_xor(acc, m, 64);
  if (lane == 0) c1[wid] = acc;
}

// ---------------- Ua f32 -> bf16 --------------------------------------------
__global__ void cvt_ua_kernel(const float* __restrict__ Ua,
                              unsigned short* __restrict__ out) {
  int i = blockIdx.x * 256 + threadIdx.x;  // 4 elements each
  float4 v = ((const float4*)Ua)[i];
  typedef __attribute__((ext_vector_type(4))) unsigned short u16x4;
  u16x4 o = {f2bf(v.x), f2bf(v.y), f2bf(v.z), f2bf(v.w)};
  *(u16x4*)(out + (size_t)i * 4) = o;
}

// ============================================================================
// 256x256x64 8-phase double-buffered bf16 GEMM + fused tanh/Va epilogue.
// A = rnnbf [Mn][Hn] bf16, Bm = Uabf [Qn][Hn] bf16; both via global_load_lds.
// LDS per buffer: A/B [256][64] bf16, row 128B, 16B-chunk swizzle
//   slot = chunk ^ (row&7); stage source pre-swizzled, reads XOR'd.
// 8 waves = 2(M) x 4(N); per-wave 128x64 output; acc[8][4] f32x4.
// Balanced frag-read spread (m201 pattern): ph1 = A-quad0 + B01 (12 b128,
// + mid-phase lgkmcnt(8) hint), ph2 = B23 (4), ph3 = A-quad1 (8), ph4 = 0
// (operands waited at ph2/ph3). LDS queue stays busy every phase instead of
// the R6 16/8/0/0 clump.
// vmcnt ledger (each STAGE_* = 2 gload16):
//   prologue: A(0)h0,h1 B(0)h0,h1 B(1)h0,h1 = 12; VMW(4) -> A(0),B(0) done.
//   steady: ph1 +A(o)h0, ph2 +A(o)h1, ph3 +B(e')h0, ph4 +B(e')h1, VMW(4)
//   [A(o),B(o) done; B(e') flies]; ph5-8 mirror with A(e'),B(o'); VMW(4).
//   tail: +A(31) at ph1/2; VMW(0) at ph4; tiles 30,31 compute-only after.
// ============================================================================
#define NKT 32  // Hn / 64

#define VMW(n)                                                                \
  do {                                                                        \
    asm volatile("s_waitcnt vmcnt(" #n ")");                                  \
    __builtin_amdgcn_sched_barrier(0);                                        \
  } while (0)
#define NOP_ ((void)0)
#define BAR __builtin_amdgcn_s_barrier()
#define LK0                                                                   \
  do {                                                                        \
    asm volatile("s_waitcnt lgkmcnt(0)");                                     \
    __builtin_amdgcn_sched_barrier(0);                                        \
  } while (0)
#define LKC8                                                                  \
  do {                                                                        \
    asm volatile("s_waitcnt lgkmcnt(8)");                                     \
    __builtin_amdgcn_sched_barrier(0);                                        \
  } while (0)
#define PIN __builtin_amdgcn_sched_barrier(0)

#define STAGE_A(kt, h)                                                        \
  do {                                                                        \
    int d_ = (kt) & 1;                                                        \
    gload16(aS + (size_t)((h) * 128) * Hn + (kt) * 64,                        \
            ldsA + d_ * 32768 + (h) * 16384 + wl);                            \
    gload16(aS + (size_t)((h) * 128 + 64) * Hn + (kt) * 64,                   \
            ldsA + d_ * 32768 + (h) * 16384 + 8192 + wl);                     \
  } while (0)

#define STAGE_B(kt, h)                                                        \
  do {                                                                        \
    int d_ = (kt) & 1;                                                        \
    gload16(bS + (size_t)((h) * 128) * Hn + (kt) * 64,                        \
            ldsB + d_ * 32768 + (h) * 16384 + wl);                            \
    gload16(bS + (size_t)((h) * 128 + 64) * Hn + (kt) * 64,                   \
            ldsB + d_ * 32768 + (h) * 16384 + 8192 + wl);                     \
  } while (0)

#define RD_A(dst, d, qm)                                                      \
  do {                                                                        \
    _Pragma("unroll") for (int ii = 0; ii < 4; ii++) {                        \
      dst[ii][0] = *(const bf16x8*)(ldsA + (d) * 32768 + rA +                 \
                                    ((qm) * 64 + ii * 16) * 128 + cA0);       \
      dst[ii][1] = *(const bf16x8*)(ldsA + (d) * 32768 + rA +                 \
                                    ((qm) * 64 + ii * 16) * 128 + cA1);       \
    }                                                                         \
  } while (0)

// read one B pair: bfr[2p], bfr[2p+1] (4 x b128)
#define RD_B2(d, p)                                                           \
  do {                                                                        \
    _Pragma("unroll") for (int jj = 0; jj < 2; jj++) {                        \
      bfr[(p) * 2 + jj][0] = *(const bf16x8*)(ldsB + (d) * 32768 + rB +       \
                                              (((p) * 2 + jj) * 16) * 128 +   \
                                              cA0);                           \
      bfr[(p) * 2 + jj][1] = *(const bf16x8*)(ldsB + (d) * 32768 + rB +       \
                                              (((p) * 2 + jj) * 16) * 128 +   \
                                              cA1);                           \
    }                                                                         \
  } while (0)

#define MM(qm, qn, A_)                                                        \
  do {                                                                        \
    __builtin_amdgcn_s_setprio(1);                                            \
    _Pragma("unroll") for (int ii = 0; ii < 4; ii++)                          \
        _Pragma("unroll") for (int jj = 0; jj < 2; jj++)                      \
            _Pragma("unroll") for (int ks = 0; ks < 2; ks++)                  \
                acc[(qm) * 4 + ii][(qn) * 2 + jj] =                           \
        __builtin_amdgcn_mfma_f32_16x16x32_bf16(                              \
            A_[ii][ks], bfr[(qn) * 2 + jj][ks],                               \
            acc[(qm) * 4 + ii][(qn) * 2 + jj], 0, 0, 0);                      \
    __builtin_amdgcn_s_setprio(0);                                            \
  } while (0)

// one K-tile = 4 phases; S1..S4 = stage issues, WEND = vmcnt wait at ph4.
// Reads spread 12/4/8/0; ph4 needs no lgkm wait (afr1 ph3, bfr23 ph2).
#define TILE4(d, S1, S2, S3, S4, WEND)                                        \
  do {                                                                        \
    RD_A(afr0, d, 0);                                                         \
    RD_B2(d, 0);                                                              \
    S1; LKC8; BAR; LK0; MM(0, 0, afr0); BAR; PIN;                             \
    RD_B2(d, 1);                                                              \
    S2; BAR; LK0; MM(0, 1, afr0); BAR; PIN;                                   \
    RD_A(afr1, d, 1);                                                         \
    S3; BAR; LK0; MM(1, 0, afr1); BAR; PIN;                                   \
    S4; BAR; MM(1, 1, afr1); WEND; BAR; PIN;                                  \
  } while (0)

__global__ __launch_bounds__(512) void gemm8_kernel(
    const unsigned short* __restrict__ A, const unsigned short* __restrict__ Bm,
    const float* __restrict__ c1, const float* __restrict__ Va,
    float* __restrict__ e) {
  __shared__ __align__(128) char lds[131072];
  __shared__ float c1s[256];
  __shared__ float Vas[256];

  const int t = threadIdx.x;
  const int l = t & 63;
  const int w = t >> 6;
  const int wr = w >> 2, wc = w & 3;

  int bid = blockIdx.x;  // 1024 blocks; 1024 % 8 == 0 -> bijective XCD swizzle
  int swz = (bid & 7) * 128 + (bid >> 3);
  const int mtile = swz >> 2;
  const int ntile = swz & 3;
  const int m0 = mtile * 256, n0 = ntile * 256;
  const int bidx = mtile >> 3;  // batch (256-row tile never straddles S=2048)

  // staging: thread t covers (row sr, slot t&7); pre-swizzled global source
  const int sr = t >> 3;              // 0..63
  const int sj = (t & 7) ^ (sr & 7);  // logical 16B-chunk index
  const unsigned short* aS = A + (size_t)(m0 + sr) * Hn + sj * 8;
  const unsigned short* bS = Bm + (size_t)(n0 + sr) * Hn + sj * 8;
  char* ldsA = lds;
  char* ldsB = lds + 65536;
  const int wl = w * 1024;

  // fragment read constants (XOR swizzle on read side)
  const int xk = l & 7;
  const int lr4 = l >> 4;
  const int cA0 = ((0 * 4 + lr4) ^ xk) * 16;
  const int cA1 = ((1 * 4 + lr4) ^ xk) * 16;
  const int rA = (wr * 128 + (l & 15)) * 128;
  const int rB = (wc * 64 + (l & 15)) * 128;

  f32x4 acc[8][4];
#pragma unroll
  for (int i = 0; i < 8; i++)
#pragma unroll
    for (int j = 0; j < 4; j++) acc[i][j] = (f32x4){0.f, 0.f, 0.f, 0.f};

  bf16x8 afr0[4][2], afr1[4][2], bfr[4][2];

  // ---- prologue: buf0 = tile0 (8 loads), buf1.B = tile1 (4 loads) ----
  STAGE_A(0, 0);
  STAGE_A(0, 1);
  STAGE_B(0, 0);
  STAGE_B(0, 1);
  STAGE_B(1, 0);
  STAGE_B(1, 1);
  PIN;
  VMW(4);  // A(0),B(0) landed; B(1) in flight
  BAR;
  PIN;

  // ---- main loop: 15 iterations, branch-free ----
#pragma unroll 1
  for (int it = 0; it < NKT / 2 - 1; ++it) {
    const int ko = 2 * it + 1;
    const int k2 = 2 * it + 2, k3 = 2 * it + 3;
    TILE4(0, STAGE_A(ko, 0), STAGE_A(ko, 1), STAGE_B(k2, 0), STAGE_B(k2, 1),
          VMW(4));
    TILE4(1, STAGE_A(k2, 0), STAGE_A(k2, 1), STAGE_B(k3, 0), STAGE_B(k3, 1),
          VMW(4));
  }

  // ---- peeled tail: tiles 30 (buf0), 31 (buf1) ----
  TILE4(0, STAGE_A(31, 0), STAGE_A(31, 1), NOP_, NOP_, VMW(0));
  TILE4(1, NOP_, NOP_, NOP_, NOP_, NOP_);

  // ---- epilogue: e[row] += sum over this block's 256 q of Va*tanh(c1+C) ----
  if (t < 256) {
    c1s[t] = c1[bidx * Qn + n0 + t];
    Vas[t] = Va[n0 + t];
  }
  __syncthreads();

#pragma unroll
  for (int i = 0; i < 8; i++) {
#pragma unroll
    for (int r = 0; r < 4; r++) {
      float sum = 0.f;
#pragma unroll
      for (int j = 0; j < 4; j++) {
        int ql = wc * 64 + j * 16 + (l & 15);
        float x = c1s[ql] + acc[i][j][r];
        float ex = __expf(2.f * x);
        sum += Vas[ql] * (1.f - 2.f / (ex + 1.f));  // tanh, saturates safely
      }
#pragma unroll
      for (int m = 8; m > 0; m >>= 1) sum += __shfl_xor(sum, m, 16);
      if ((l & 15) == 0) {
        int row = m0 + wr * 128 + i * 16 + (l >> 4) * 4 + r;
        atomicAdd(&e[row], sum);
      }
    }
  }
}

// ---------------- softmax over S per batch ----------------------------------
__global__ void softmax_kernel(const float* __restrict__ e,
                               const int* __restrict__ mask,
                               float* __restrict__ a) {
  const int b = blockIdx.x;
  const int t = threadIdx.x;
  const int lane = t & 63;
  const int w = t >> 6;
  __shared__ float red[8];
  float v[8];
  float mx = -3.0e38f;
#pragma unroll
  for (int i = 0; i < 8; i++) {
    int s = i * 256 + t;
    float x = e[(size_t)b * Sn + s];
    if (mask[(size_t)b * Sn + s] == 0) x = -1e32f;
    v[i] = x;
    mx = fmaxf(mx, x);
  }
#pragma unroll
  for (int m = 32; m > 0; m >>= 1) mx = fmaxf(mx, __shfl_xor(mx, m, 64));
  if (lane == 0) red[w] = mx;
  __syncthreads();
  mx = fmaxf(fmaxf(red[0], red[1]), fmaxf(red[2], red[3]));
  float sm = 0.f;
#pragma unroll
  for (int i = 0; i < 8; i++) {
    v[i] = __expf(v[i] - mx);
    sm += v[i];
  }
#pragma unroll
  for (int m = 32; m > 0; m >>= 1) sm += __shfl_xor(sm, m, 64);
  if (lane == 0) red[4 + w] = sm;
  __syncthreads();
  sm = red[4] + red[5] + red[6] + red[7];
  float inv = 1.f / sm;
#pragma unroll
  for (int i = 0; i < 8; i++) a[(size_t)b * Sn + i * 256 + t] = v[i] * inv;
}

// ---------------- context from bf16 rnn -------------------------------------
__global__ void ctx_bf16_kernel(const unsigned short* __restrict__ rnnbf,
                                const float* __restrict__ a,
                                float* __restrict__ out) {
  const int b = blockIdx.y;
  const int sc = blockIdx.x;  // s-chunk of 256
  const int t = threadIdx.x;
  __shared__ float as_[256];
  as_[t] = a[(size_t)b * Sn + sc * 256 + t];
  __syncthreads();
  float ac[8] = {0, 0, 0, 0, 0, 0, 0, 0};
  const unsigned short* base =
      rnnbf + ((size_t)b * Sn + sc * 256) * Hn + t * 8;
  for (int s = 0; s < 256; s++) {
    float wgt = as_[s];
    bf16x8 v = *(const bf16x8*)(base + (size_t)s * Hn);
#pragma unroll
    for (int k = 0; k < 8; k++) ac[k] += wgt * bf2f(v[k]);
  }
  float* o = out + (size_t)b * Hn + t * 8;
#pragma unroll
  for (int k = 0; k < 8; k++) atomicAdd(o + k, ac[k]);
}

extern "C" void kernel_launch(void* const* d_in, const int* in_sizes, int n_in,
                              void* d_out, int out_size, void* d_ws,
                              size_t ws_size, hipStream_t stream) {
  const float* rnn = (const float*)d_in[0];
  const float* rev = (const float*)d_in[1];
  const int* mask = (const int*)d_in[2];
  const float* Wa = (const float*)d_in[3];
  const float* Ua = (const float*)d_in[4];
  const float* Va = (const float*)d_in[5];

  const size_t RNBF = (size_t)Mn * Hn * 2;  // 256 MiB bf16 rnn copy
  char* w = (char*)d_ws;
  unsigned short* rnnbf = (unsigned short*)w;
  unsigned short* Uabf = (unsigned short*)(w + RNBF);
  float* c1 = (float*)(w + RNBF + 4194304);
  float* e = (float*)(w + RNBF + 4194304 + 131072);
  float* a = (float*)(w + RNBF + 4194304 + 131072 + 262144);

  hipMemsetAsync(e, 0, (size_t)Mn * sizeof(float), stream);
  hipMemsetAsync(d_out, 0, (size_t)out_size * sizeof(float), stream);

  cvt_rnn_kernel<<<4096, 256, 0, stream>>>(rnn, rnnbf);
  cvt_ua_kernel<<<(Qn * Hn / 4) / 256, 256, 0, stream>>>(Ua, Uabf);
  c1_kernel<<<(Bn * Qn) / 4, 256, 0, stream>>>(rev, Wa, c1);

  gemm8_kernel<<<(Mn / 256) * (Qn / 256), 512, 0, stream>>>(rnnbf, Uabf, c1,
                                                            Va, e);
  softmax_kernel<<<Bn, 256, 0, stream>>>(e, mask, a);

  dim3 gc(8, Bn);
  ctx_bf16_kernel<<<gc, 256, 0, stream>>>(rnnbf, a, (float*)d_out);
}

// Round 8
// 492.693 us; speedup vs baseline: 1.0184x; 1.0184x over previous
//
#include <hip/hip_runtime.h>
#include <hip/hip_bf16.h>

#define Bn 32
#define Sn 2048
#define Hn 2048
#define Qn 1024
#define Mn (Bn * Sn)

typedef __attribute__((ext_vector_type(8))) short bf16x8;
typedef __attribute__((ext_vector_type(4))) float f32x4;

__device__ __forceinline__ unsigned short f2bf(float x) {
  unsigned int u = __float_as_uint(x);
  unsigned int r = (u + 0x7FFFu + ((u >> 16) & 1u)) >> 16;  // RNE
  return (unsigned short)r;
}

__device__ __forceinline__ float bf2f(short s) {
  return __uint_as_float(((unsigned int)(unsigned short)s) << 16);
}

__device__ __forceinline__ unsigned int cvtpk(float lo, float hi) {
  unsigned int r;
  asm("v_cvt_pk_bf16_f32 %0, %1, %2" : "=v"(r) : "v"(lo), "v"(hi));
  return r;
}

__device__ __forceinline__ void gload16(const void* g, void* l) {
  __builtin_amdgcn_global_load_lds(
      (const __attribute__((address_space(1))) unsigned int*)g,
      (__attribute__((address_space(3))) unsigned int*)l, 16, 0, 0);
}

// ---------------- rnn f32 -> bf16 (grid-stride, 8 elems/thread/iter) --------
__global__ void cvt_rnn_kernel(const float* __restrict__ in,
                               unsigned short* __restrict__ out) {
  const size_t total8 = (size_t)Mn * Hn / 8;
  size_t i = (size_t)blockIdx.x * 256 + threadIdx.x;
  const size_t stride = (size_t)gridDim.x * 256;
  for (; i < total8; i += stride) {
    float4 v0 = ((const float4*)in)[i * 2];
    float4 v1 = ((const float4*)in)[i * 2 + 1];
    union { unsigned int u[4]; bf16x8 v; } pk;
    pk.u[0] = cvtpk(v0.x, v0.y);
    pk.u[1] = cvtpk(v0.z, v0.w);
    pk.u[2] = cvtpk(v1.x, v1.y);
    pk.u[3] = cvtpk(v1.z, v1.w);
    *(bf16x8*)(out + i * 8) = pk.v;
  }
}

// ---------------- c1[b,q] = sum_k rev[b,k] * Wa[q,k] ------------------------
__global__ void c1_kernel(const float* __restrict__ rev,
                          const float* __restrict__ Wa,
                          float* __restrict__ c1) {
  int wid = (blockIdx.x * 256 + threadIdx.x) >> 6;
  int lane = threadIdx.x & 63;
  int b = wid >> 10;
  int q = wid & (Qn - 1);
  const float* rv = rev + (size_t)b * Qn;
  const float* wr = Wa + (size_t)q * Qn;
  float acc = 0.f;
#pragma unroll
  for (int k = 0; k < Qn; k += 64) acc += rv[k + lane] * wr[k + lane];
#pragma unroll
  for (int m = 32; m > 0; m >>= 1) acc += __shfl_xor(acc, m, 64);
  if (lane == 0) c1[wid] = acc;
}

// ---------------- Ua f32 -> bf16 --------------------------------------------
__global__ void cvt_ua_kernel(const float* __restrict__ Ua,
                              unsigned short* __restrict__ out) {
  int i = blockIdx.x * 256 + threadIdx.x;  // 4 elements each
  float4 v = ((const float4*)Ua)[i];
  typedef __attribute__((ext_vector_type(4))) unsigned short u16x4;
  u16x4 o = {f2bf(v.x), f2bf(v.y), f2bf(v.z), f2bf(v.w)};
  *(u16x4*)(out + (size_t)i * 4) = o;
}

// ============================================================================
// 256x256x64 8-phase double-buffered bf16 GEMM + fused tanh/Va epilogue.
// A = rnnbf [Mn][Hn] bf16, Bm = Uabf [Qn][Hn] bf16; both via global_load_lds.
// LDS per buffer: A/B [256][64] bf16, row 128B, 16B-chunk swizzle
//   slot = chunk ^ (row&7); stage source pre-swizzled, reads XOR'd.
// 8 waves = 2(M) x 4(N); per-wave 128x64 output; acc[8][4] f32x4.
//
// R8 SYNC STRUCTURE: single barrier for phases 1-3 (double barrier only at
// the vmcnt-publish phase ph4/ph8). Waves may skew < 1 phase -> one wave's
// ds_reads fill the LDS pipe under another wave's MFMA cluster (we are
// LDS-throughput-bound: 192 b128/CU/K-tile ~ 2300 cyc vs MFMA 620 cyc).
// Hazard audit: buffer-X stage issue is >= 2 barriers after buffer-X's last
// read-wait (lgkmcnt(0)); vmcnt is per-wave so VMW(4) is followed by a
// barrier before any cross-wave read of the staged buffer.
// vmcnt ledger (each STAGE_* = 2 gload16):
//   prologue: A(0) 4, B(0) 4, B(1) 4 = 12 out; VMW(4) -> A(0),B(0) landed.
//   steady: ph1 +A(o)h0, ph2 +A(o)h1, ph3 +B(e')h0, ph4 +B(e')h1 then VMW(4)
//   [A(o),B(o) landed; B(e') 4 in flight]; ph5-8 mirror; tail VMW(0).
// ============================================================================
#define NKT 32  // Hn / 64

#define VMW(n)                                                                \
  do {                                                                        \
    asm volatile("s_waitcnt vmcnt(" #n ")");                                  \
    __builtin_amdgcn_sched_barrier(0);                                        \
  } while (0)
#define NOP_ ((void)0)
#define BAR __builtin_amdgcn_s_barrier()
#define LK0                                                                   \
  do {                                                                        \
    asm volatile("s_waitcnt lgkmcnt(0)");                                     \
    __builtin_amdgcn_sched_barrier(0);                                        \
  } while (0)
#define PIN __builtin_amdgcn_sched_barrier(0)

#define STAGE_A(kt, h)                                                        \
  do {                                                                        \
    int d_ = (kt) & 1;                                                        \
    gload16(aS + (size_t)((h) * 128) * Hn + (kt) * 64,                        \
            ldsA + d_ * 32768 + (h) * 16384 + wl);                            \
    gload16(aS + (size_t)((h) * 128 + 64) * Hn + (kt) * 64,                   \
            ldsA + d_ * 32768 + (h) * 16384 + 8192 + wl);                     \
  } while (0)

#define STAGE_B(kt, h)                                                        \
  do {                                                                        \
    int d_ = (kt) & 1;                                                        \
    gload16(bS + (size_t)((h) * 128) * Hn + (kt) * 64,                        \
            ldsB + d_ * 32768 + (h) * 16384 + wl);                            \
    gload16(bS + (size_t)((h) * 128 + 64) * Hn + (kt) * 64,                   \
            ldsB + d_ * 32768 + (h) * 16384 + 8192 + wl);                     \
  } while (0)

#define RD_A(dst, d, qm)                                                      \
  do {                                                                        \
    _Pragma("unroll") for (int ii = 0; ii < 4; ii++) {                        \
      dst[ii][0] = *(const bf16x8*)(ldsA + (d) * 32768 + rA +                 \
                                    ((qm) * 64 + ii * 16) * 128 + cA0);       \
      dst[ii][1] = *(const bf16x8*)(ldsA + (d) * 32768 + rA +                 \
                                    ((qm) * 64 + ii * 16) * 128 + cA1);       \
    }                                                                         \
  } while (0)

// read one B pair: bfr[2p], bfr[2p+1] (4 x b128)
#define RD_B2(d, p)                                                           \
  do {                                                                        \
    _Pragma("unroll") for (int jj = 0; jj < 2; jj++) {                        \
      bfr[(p) * 2 + jj][0] = *(const bf16x8*)(ldsB + (d) * 32768 + rB +       \
                                              (((p) * 2 + jj) * 16) * 128 +   \
                                              cA0);                           \
      bfr[(p) * 2 + jj][1] = *(const bf16x8*)(ldsB + (d) * 32768 + rB +       \
                                              (((p) * 2 + jj) * 16) * 128 +   \
                                              cA1);                           \
    }                                                                         \
  } while (0)

#define MM(qm, qn, A_)                                                        \
  do {                                                                        \
    __builtin_amdgcn_s_setprio(1);                                            \
    _Pragma("unroll") for (int ii = 0; ii < 4; ii++)                          \
        _Pragma("unroll") for (int jj = 0; jj < 2; jj++)                      \
            _Pragma("unroll") for (int ks = 0; ks < 2; ks++)                  \
                acc[(qm) * 4 + ii][(qn) * 2 + jj] =                           \
        __builtin_amdgcn_mfma_f32_16x16x32_bf16(                              \
            A_[ii][ks], bfr[(qn) * 2 + jj][ks],                               \
            acc[(qm) * 4 + ii][(qn) * 2 + jj], 0, 0, 0);                      \
    __builtin_amdgcn_s_setprio(0);                                            \
  } while (0)

// one K-tile = 4 phases. Single barrier ph1-3; double barrier (vmcnt publish)
// at ph4. Reads spread 12/4/8/0; ph4 MFMA operands waited at ph2/ph3.
#define TILE4(d, S1, S2, S3, S4, WEND)                                        \
  do {                                                                        \
    RD_A(afr0, d, 0);                                                         \
    RD_B2(d, 0);                                                              \
    S1; BAR; LK0; MM(0, 0, afr0);                                             \
    RD_B2(d, 1);                                                              \
    S2; BAR; LK0; MM(0, 1, afr0);                                             \
    RD_A(afr1, d, 1);                                                         \
    S3; BAR; LK0; MM(1, 0, afr1);                                             \
    S4; BAR; MM(1, 1, afr1); WEND; BAR; PIN;                                  \
  } while (0)

__global__ __launch_bounds__(512) void gemm8_kernel(
    const unsigned short* __restrict__ A, const unsigned short* __restrict__ Bm,
    const float* __restrict__ c1, const float* __restrict__ Va,
    float* __restrict__ e) {
  __shared__ __align__(128) char lds[131072];
  __shared__ float c1s[256];
  __shared__ float Vas[256];

  const int t = threadIdx.x;
  const int l = t & 63;
  const int w = t >> 6;
  const int wr = w >> 2, wc = w & 3;

  int bid = blockIdx.x;  // 1024 blocks; 1024 % 8 == 0 -> bijective XCD swizzle
  int swz = (bid & 7) * 128 + (bid >> 3);
  const int mtile = swz >> 2;
  const int ntile = swz & 3;
  const int m0 = mtile * 256, n0 = ntile * 256;
  const int bidx = mtile >> 3;  // batch (256-row tile never straddles S=2048)

  // staging: thread t covers (row sr, slot t&7); pre-swizzled global source
  const int sr = t >> 3;              // 0..63
  const int sj = (t & 7) ^ (sr & 7);  // logical 16B-chunk index
  const unsigned short* aS = A + (size_t)(m0 + sr) * Hn + sj * 8;
  const unsigned short* bS = Bm + (size_t)(n0 + sr) * Hn + sj * 8;
  char* ldsA = lds;
  char* ldsB = lds + 65536;
  const int wl = w * 1024;

  // fragment read constants (XOR swizzle on read side)
  const int xk = l & 7;
  const int lr4 = l >> 4;
  const int cA0 = ((0 * 4 + lr4) ^ xk) * 16;
  const int cA1 = ((1 * 4 + lr4) ^ xk) * 16;
  const int rA = (wr * 128 + (l & 15)) * 128;
  const int rB = (wc * 64 + (l & 15)) * 128;

  f32x4 acc[8][4];
#pragma unroll
  for (int i = 0; i < 8; i++)
#pragma unroll
    for (int j = 0; j < 4; j++) acc[i][j] = (f32x4){0.f, 0.f, 0.f, 0.f};

  bf16x8 afr0[4][2], afr1[4][2], bfr[4][2];

  // ---- prologue: buf0 = tile0 (8 loads), buf1.B = tile1 (4 loads) ----
  STAGE_A(0, 0);
  STAGE_A(0, 1);
  STAGE_B(0, 0);
  STAGE_B(0, 1);
  STAGE_B(1, 0);
  STAGE_B(1, 1);
  PIN;
  VMW(4);  // A(0),B(0) landed; B(1) in flight
  BAR;
  PIN;

  // ---- main loop: 15 iterations, branch-free ----
#pragma unroll 1
  for (int it = 0; it < NKT / 2 - 1; ++it) {
    const int ko = 2 * it + 1;
    const int k2 = 2 * it + 2, k3 = 2 * it + 3;
    TILE4(0, STAGE_A(ko, 0), STAGE_A(ko, 1), STAGE_B(k2, 0), STAGE_B(k2, 1),
          VMW(4));
    TILE4(1, STAGE_A(k2, 0), STAGE_A(k2, 1), STAGE_B(k3, 0), STAGE_B(k3, 1),
          VMW(4));
  }

  // ---- peeled tail: tiles 30 (buf0), 31 (buf1) ----
  TILE4(0, STAGE_A(31, 0), STAGE_A(31, 1), NOP_, NOP_, VMW(0));
  TILE4(1, NOP_, NOP_, NOP_, NOP_, NOP_);

  // ---- epilogue: e[row] += sum over this block's 256 q of Va*tanh(c1+C) ----
  if (t < 256) {
    c1s[t] = c1[bidx * Qn + n0 + t];
    Vas[t] = Va[n0 + t];
  }
  __syncthreads();

#pragma unroll
  for (int i = 0; i < 8; i++) {
#pragma unroll
    for (int r = 0; r < 4; r++) {
      float sum = 0.f;
#pragma unroll
      for (int j = 0; j < 4; j++) {
        int ql = wc * 64 + j * 16 + (l & 15);
        float x = c1s[ql] + acc[i][j][r];
        float ex = __expf(2.f * x);
        sum += Vas[ql] * (1.f - 2.f / (ex + 1.f));  // tanh, saturates safely
      }
#pragma unroll
      for (int m = 8; m > 0; m >>= 1) sum += __shfl_xor(sum, m, 16);
      if ((l & 15) == 0) {
        int row = m0 + wr * 128 + i * 16 + (l >> 4) * 4 + r;
        atomicAdd(&e[row], sum);
      }
    }
  }
}

// ---------------- softmax over S per batch ----------------------------------
__global__ void softmax_kernel(const float* __restrict__ e,
                               const int* __restrict__ mask,
                               float* __restrict__ a) {
  const int b = blockIdx.x;
  const int t = threadIdx.x;
  const int lane = t & 63;
  const int w = t >> 6;
  __shared__ float red[8];
  float v[8];
  float mx = -3.0e38f;
#pragma unroll
  for (int i = 0; i < 8; i++) {
    int s = i * 256 + t;
    float x = e[(size_t)b * Sn + s];
    if (mask[(size_t)b * Sn + s] == 0) x = -1e32f;
    v[i] = x;
    mx = fmaxf(mx, x);
  }
#pragma unroll
  for (int m = 32; m > 0; m >>= 1) mx = fmaxf(mx, __shfl_xor(mx, m, 64));
  if (lane == 0) red[w] = mx;
  __syncthreads();
  mx = fmaxf(fmaxf(red[0], red[1]), fmaxf(red[2], red[3]));
  float sm = 0.f;
#pragma unroll
  for (int i = 0; i < 8; i++) {
    v[i] = __expf(v[i] - mx);
    sm += v[i];
  }
#pragma unroll
  for (int m = 32; m > 0; m >>= 1) sm += __shfl_xor(sm, m, 64);
  if (lane == 0) red[4 + w] = sm;
  __syncthreads();
  sm = red[4] + red[5] + red[6] + red[7];
  float inv = 1.f / sm;
#pragma unroll
  for (int i = 0; i < 8; i++) a[(size_t)b * Sn + i * 256 + t] = v[i] * inv;
}

// ---------------- context from bf16 rnn -------------------------------------
__global__ void ctx_bf16_kernel(const unsigned short* __restrict__ rnnbf,
                                const float* __restrict__ a,
                                float* __restrict__ out) {
  const int b = blockIdx.y;
  const int sc = blockIdx.x;  // s-chunk of 256
  const int t = threadIdx.x;
  __shared__ float as_[256];
  as_[t] = a[(size_t)b * Sn + sc * 256 + t];
  __syncthreads();
  float ac[8] = {0, 0, 0, 0, 0, 0, 0, 0};
  const unsigned short* base =
      rnnbf + ((size_t)b * Sn + sc * 256) * Hn + t * 8;
  for (int s = 0; s < 256; s++) {
    float wgt = as_[s];
    bf16x8 v = *(const bf16x8*)(base + (size_t)s * Hn);
#pragma unroll
    for (int k = 0; k < 8; k++) ac[k] += wgt * bf2f(v[k]);
  }
  float* o = out + (size_t)b * Hn + t * 8;
#pragma unroll
  for (int k = 0; k < 8; k++) atomicAdd(o + k, ac[k]);
}

extern "C" void kernel_launch(void* const* d_in, const int* in_sizes, int n_in,
                              void* d_out, int out_size, void* d_ws,
                              size_t ws_size, hipStream_t stream) {
  const float* rnn = (const float*)d_in[0];
  const float* rev = (const float*)d_in[1];
  const int* mask = (const int*)d_in[2];
  const float* Wa = (const float*)d_in[3];
  const float* Ua = (const float*)d_in[4];
  const float* Va = (const float*)d_in[5];

  const size_t RNBF = (size_t)Mn * Hn * 2;  // 256 MiB bf16 rnn copy
  char* w = (char*)d_ws;
  unsigned short* rnnbf = (unsigned short*)w;
  unsigned short* Uabf = (unsigned short*)(w + RNBF);
  float* c1 = (float*)(w + RNBF + 4194304);
  float* e = (float*)(w + RNBF + 4194304 + 131072);
  float* a = (float*)(w + RNBF + 4194304 + 131072 + 262144);

  hipMemsetAsync(e, 0, (size_t)Mn * sizeof(float), stream);
  hipMemsetAsync(d_out, 0, (size_t)out_size * sizeof(float), stream);

  cvt_rnn_kernel<<<4096, 256, 0, stream>>>(rnn, rnnbf);
  cvt_ua_kernel<<<(Qn * Hn / 4) / 256, 256, 0, stream>>>(Ua, Uabf);
  c1_kernel<<<(Bn * Qn) / 4, 256, 0, stream>>>(rev, Wa, c1);

  gemm8_kernel<<<(Mn / 256) * (Qn / 256), 512, 0, stream>>>(rnnbf, Uabf, c1,
                                                            Va, e);
  softmax_kernel<<<Bn, 256, 0, stream>>>(e, mask, a);

  dim3 gc(8, Bn);
  ctx_bf16_kernel<<<gc, 256, 0, stream>>>(rnnbf, a, (float*)d_out);
}